// Round 1
// baseline (1055.479 us; speedup 1.0000x reference)
//
#include <hip/hip_runtime.h>

#define NPOS 21824          // 16384+4096+1024+256+64 positions per image
#define NC   3320           // 1000+1000+1000+256+64 candidates per image
#define NEGV -1000000000.0f
#define MINS 0.05f

struct Ptrs { const float* cls[5]; const float* reg[5]; const float* ctr[5]; };

__device__ __forceinline__ float sigf(float x) { return 1.0f / (1.0f + expf(-x)); }

// ---------------- Kernel A: score / class / box per position ----------------
__global__ void k_score(Ptrs P, float* scoreAll, int* clsAll, float4* boxAll) {
    int p = blockIdx.x * blockDim.x + threadIdx.x;
    if (p >= NPOS) return;
    int img = blockIdx.y;
    int lvl, base, lw, stride;
    if (p < 16384)      { lvl = 0; base = 0;     lw = 7; stride = 8;   }
    else if (p < 20480) { lvl = 1; base = 16384; lw = 6; stride = 16;  }
    else if (p < 21504) { lvl = 2; base = 20480; lw = 5; stride = 32;  }
    else if (p < 21760) { lvl = 3; base = 21504; lw = 4; stride = 64;  }
    else                { lvl = 4; base = 21760; lw = 3; stride = 128; }
    int pl = p - base;
    int h = pl >> lw, w = pl & ((1 << lw) - 1);
    long long lidx = (long long)img * (1 << (2 * lw)) + pl;

    const float4* c4 = (const float4*)(P.cls[lvl] + lidx * 80);
    float mx = -3.4e38f; int mi = 0;
#pragma unroll
    for (int j = 0; j < 20; ++j) {
        float4 v = c4[j];
        if (v.x > mx) { mx = v.x; mi = 4 * j;     }
        if (v.y > mx) { mx = v.y; mi = 4 * j + 1; }
        if (v.z > mx) { mx = v.z; mi = 4 * j + 2; }
        if (v.w > mx) { mx = v.w; mi = 4 * j + 3; }
    }
    float ct = P.ctr[lvl][lidx];
    float sc = sqrtf(sigf(mx) * sigf(ct));   // sigmoid(max) == max(sigmoid)

    float4 rg = ((const float4*)P.reg[lvl])[lidx];
    float x = (w + 0.5f) * (float)stride;
    float y = (h + 0.5f) * (float)stride;
    int ix1 = (int)(x - expf(rg.x));
    int iy1 = (int)(y - expf(rg.y));
    int ix2 = (int)(x + expf(rg.z));
    int iy2 = (int)(y + expf(rg.w));
    ix1 = max(ix1, 0); iy1 = max(iy1, 0);
    ix2 = min(ix2, 1023); iy2 = min(iy2, 1023);

    int o = img * NPOS + p;
    scoreAll[o] = sc;
    clsAll[o]   = mi;
    boxAll[o]   = make_float4((float)ix1, (float)iy1, (float)ix2, (float)iy2);
}

// ------- Kernel B: exact k=1000 radix select per (image, level 0..2) --------
__global__ void k_select(const float* scoreAll, unsigned int* kth, int* eqcnt,
                         int* eqidx, int* ccnt) {
    const int baseArr[3] = {0, 16384, 20480};
    const int NlArr[3]   = {16384, 4096, 1024};
    int il  = blockIdx.x;            // img*3 + lvl
    int img = il / 3, lvl = il % 3;
    int Nl  = NlArr[lvl];
    const unsigned int* sb = (const unsigned int*)scoreAll + img * NPOS + baseArr[lvl];

    __shared__ int hist[2048];
    __shared__ unsigned int shPrefix, shKth;
    __shared__ int shK, listCnt;
    __shared__ int list[64];
    int tid = threadIdx.x;
    if (tid == 0) { shK = 1000; shPrefix = 0; listCnt = 0; ccnt[il] = 0; }

    // pass 0: bits [31:21]
    for (int i = tid; i < 2048; i += 256) hist[i] = 0;
    __syncthreads();
    for (int i = tid; i < Nl; i += 256) atomicAdd(&hist[sb[i] >> 21], 1);
    __syncthreads();
    if (tid == 0) {
        int K = shK, cum = 0;
        for (int b = 2047; b >= 0; --b) {
            cum += hist[b];
            if (cum >= K) { shPrefix = (unsigned int)b << 21; shK = K - (cum - hist[b]); break; }
        }
    }
    __syncthreads();
    unsigned int pref1 = shPrefix;

    // pass 1: bits [20:10]
    for (int i = tid; i < 2048; i += 256) hist[i] = 0;
    __syncthreads();
    for (int i = tid; i < Nl; i += 256) {
        unsigned int b = sb[i];
        if ((b >> 21) == (pref1 >> 21)) atomicAdd(&hist[(b >> 10) & 2047], 1);
    }
    __syncthreads();
    if (tid == 0) {
        int K = shK, cum = 0;
        for (int b = 2047; b >= 0; --b) {
            cum += hist[b];
            if (cum >= K) { shPrefix = pref1 | ((unsigned int)b << 10); shK = K - (cum - hist[b]); break; }
        }
    }
    __syncthreads();
    unsigned int pref2 = shPrefix;

    // pass 2: bits [9:0]
    for (int i = tid; i < 2048; i += 256) hist[i] = 0;
    __syncthreads();
    for (int i = tid; i < Nl; i += 256) {
        unsigned int b = sb[i];
        if ((b >> 10) == (pref2 >> 10)) atomicAdd(&hist[b & 1023], 1);
    }
    __syncthreads();
    if (tid == 0) {
        int K = shK, cum = 0;
        for (int b = 1023; b >= 0; --b) {
            cum += hist[b];
            if (cum >= K) { shKth = pref2 | (unsigned int)b; shK = K - (cum - hist[b]); break; }
        }
        kth[il] = shKth;
    }
    __syncthreads();

    // collect indices equal to kth value; take lowest-index ones (top_k tie rule)
    unsigned int kv = shKth;
    for (int i = tid; i < Nl; i += 256) {
        if (sb[i] == kv) { int t = atomicAdd(&listCnt, 1); if (t < 64) list[t] = i; }
    }
    __syncthreads();
    if (tid == 0) {
        int m = min(listCnt, 64);
        for (int a = 1; a < m; ++a) {             // insertion sort ascending
            int v = list[a], b2 = a - 1;
            while (b2 >= 0 && list[b2] > v) { list[b2 + 1] = list[b2]; --b2; }
            list[b2 + 1] = v;
        }
        int take = min(shK, m);
        eqcnt[il] = take;
        for (int q = 0; q < take; ++q) eqidx[il * 64 + q] = list[q];
    }
}

// --------------- Kernel C: compact selected candidates ----------------------
__global__ void k_compact(const float* scoreAll, const int* clsAll, const float4* boxAll,
                          const unsigned int* kth, const int* eqcnt, const int* eqidx,
                          int* ccnt, float* cS, float* cC, float4* cB, float* cA) {
    int p = blockIdx.x * blockDim.x + threadIdx.x;
    if (p >= NPOS) return;
    int img = blockIdx.y;
    int lvl, base, cbase;
    if (p < 16384)      { lvl = 0; base = 0;     cbase = 0;    }
    else if (p < 20480) { lvl = 1; base = 16384; cbase = 1000; }
    else if (p < 21504) { lvl = 2; base = 20480; cbase = 2000; }
    else if (p < 21760) { lvl = 3; base = 21504; cbase = 3000; }
    else                { lvl = 4; base = 21760; cbase = 3256; }
    int pl = p - base;
    int o  = img * NPOS + p;
    float sc = scoreAll[o];
    int slot;
    if (lvl < 3) {
        int il = img * 3 + lvl;
        unsigned int bits = __float_as_uint(sc);
        unsigned int kb = kth[il];
        bool sel = bits > kb;
        if (!sel && bits == kb) {
            int ec = eqcnt[il];
            for (int q = 0; q < ec; ++q)
                if (eqidx[il * 64 + q] == pl) { sel = true; break; }
        }
        if (!sel) return;
        slot = cbase + atomicAdd(&ccnt[il], 1);
    } else {
        slot = cbase + pl;
    }
    int co = img * NC + slot;
    float4 b = boxAll[o];
    cS[co] = sc;
    cC[co] = (float)clsAll[o];
    cB[co] = b;
    cA[co] = (b.z - b.x) * (b.w - b.y);
}

// ------------------- Kernel D: sequential NMS per image ---------------------
__global__ __launch_bounds__(256) void k_nms(const float* cS, const float* cC,
                                             const float4* cB, const float* cA,
                                             float* out) {
    int img = blockIdx.x;
    int tid = threadIdx.x;
    __shared__ float s[NC];
    __shared__ float pv[4];
    __shared__ int   pi[4];
    __shared__ int   sIdx;
    __shared__ float sVal;
    const float*  S = cS + img * NC;
    const float*  C = cC + img * NC;
    const float4* B = cB + img * NC;
    const float*  A = cA + img * NC;

    for (int i = tid; i < NC; i += 256) { float v = S[i]; s[i] = (v > MINS) ? v : NEGV; }
    __syncthreads();

    float* outS = out + img * 100;
    float* outC = out + 800 + img * 100;
    float* outB = out + 1600 + img * 400;
    int lane = tid & 63, wv = tid >> 6;
    int det = 100;

    for (int it = 0; it < 100; ++it) {
        // argmax (first-occurrence tie-break) over s[]
        float bv = NEGV; int bi = NC;
        for (int i = tid; i < NC; i += 256) {
            float v = s[i];
            if (v > bv || (v == bv && i < bi)) { bv = v; bi = i; }
        }
#pragma unroll
        for (int off = 32; off > 0; off >>= 1) {
            float ov = __shfl_down(bv, off);
            int   oi = __shfl_down(bi, off);
            if (ov > bv || (ov == bv && oi < bi)) { bv = ov; bi = oi; }
        }
        if (lane == 0) { pv[wv] = bv; pi[wv] = bi; }
        __syncthreads();
        if (tid == 0) {
            bv = pv[0]; bi = pi[0];
            for (int q = 1; q < 4; ++q)
                if (pv[q] > bv || (pv[q] == bv && pi[q] < bi)) { bv = pv[q]; bi = pi[q]; }
            sIdx = bi; sVal = bv;
            bool ok = bv > MINS;
            float4 bb = B[bi];
            outS[it] = ok ? bv : -1.0f;
            outC[it] = ok ? C[bi] : -1.0f;
            outB[4 * it + 0] = ok ? bb.x : -1.0f;
            outB[4 * it + 1] = ok ? bb.y : -1.0f;
            outB[4 * it + 2] = ok ? bb.z : -1.0f;
            outB[4 * it + 3] = ok ? bb.w : -1.0f;
        }
        __syncthreads();
        int mi = sIdx; float mv = sVal;
        if (!(mv > MINS)) { det = it + 1; break; }   // ok monotone-false afterwards
        float4 bb = B[mi];
        float  ba = A[mi];
        for (int i = tid; i < NC; i += 256) {
            float4 cb = B[i];
            float iw = fmaxf(fminf(cb.z, bb.z) - fmaxf(cb.x, bb.x), 0.0f);
            float ih = fmaxf(fminf(cb.w, bb.w) - fmaxf(cb.y, bb.y), 0.0f);
            float inter = iw * ih;
            float iou = inter / (A[i] + ba - inter + 1e-12f);
            if (iou > 0.6f) s[i] = NEGV;
        }
        if (tid == 0) s[mi] = NEGV;
        __syncthreads();
    }
    // fill remaining slots with -1 (matches reference once ok==false)
    for (int k = det + tid; k < 100; k += 256) {
        outS[k] = -1.0f; outC[k] = -1.0f;
        outB[4 * k + 0] = -1.0f; outB[4 * k + 1] = -1.0f;
        outB[4 * k + 2] = -1.0f; outB[4 * k + 3] = -1.0f;
    }
}

extern "C" void kernel_launch(void* const* d_in, const int* in_sizes, int n_in,
                              void* d_out, int out_size, void* d_ws, size_t ws_size,
                              hipStream_t stream) {
    // setup_inputs() dict order is interleaved: cls0,reg0,ctr0,cls1,... — detect.
    Ptrs P;
    bool interleaved = (in_sizes[1] == 8 * 128 * 128 * 4);
    for (int i = 0; i < 5; ++i) {
        if (interleaved) {
            P.cls[i] = (const float*)d_in[3 * i];
            P.reg[i] = (const float*)d_in[3 * i + 1];
            P.ctr[i] = (const float*)d_in[3 * i + 2];
        } else {
            P.cls[i] = (const float*)d_in[i];
            P.reg[i] = (const float*)d_in[5 + i];
            P.ctr[i] = (const float*)d_in[10 + i];
        }
    }

    char* wbase = (char*)d_ws;
    size_t off = 0;
    auto alloc = [&](size_t bytes) -> void* {
        void* r = wbase + off;
        off += (bytes + 255) & ~(size_t)255;
        return r;
    };
    float*        scoreAll = (float*)alloc((size_t)8 * NPOS * 4);
    int*          clsAll   = (int*)alloc((size_t)8 * NPOS * 4);
    float4*       boxAll   = (float4*)alloc((size_t)8 * NPOS * 16);
    unsigned int* kth      = (unsigned int*)alloc(24 * 4);
    int*          eqcnt    = (int*)alloc(24 * 4);
    int*          eqidx    = (int*)alloc(24 * 64 * 4);
    int*          ccnt     = (int*)alloc(24 * 4);
    float*        cS       = (float*)alloc((size_t)8 * NC * 4);
    float*        cC       = (float*)alloc((size_t)8 * NC * 4);
    float4*       cB       = (float4*)alloc((size_t)8 * NC * 16);
    float*        cA       = (float*)alloc((size_t)8 * NC * 4);

    dim3 gA((NPOS + 255) / 256, 8);
    k_score  <<<gA, 256, 0, stream>>>(P, scoreAll, clsAll, boxAll);
    k_select <<<24, 256, 0, stream>>>(scoreAll, kth, eqcnt, eqidx, ccnt);
    k_compact<<<gA, 256, 0, stream>>>(scoreAll, clsAll, boxAll, kth, eqcnt, eqidx,
                                      ccnt, cS, cC, cB, cA);
    k_nms    <<<8, 256, 0, stream>>>(cS, cC, cB, cA, (float*)d_out);
}

// Round 2
// 556.535 us; speedup vs baseline: 1.8965x; 1.8965x over previous
//
#include <hip/hip_runtime.h>

#define NPOS 21824          // 16384+4096+1024+256+64 positions per image
#define NC   3320           // 1000+1000+1000+256+64 candidates per image
#define NEGV -1000000000.0f
#define MINS 0.05f

struct Ptrs { const float* cls[5]; const float* reg[5]; const float* ctr[5]; };

__device__ __forceinline__ float sigf(float x) { return 1.0f / (1.0f + expf(-x)); }

// ---------------- Kernel A: score / class / box per position ----------------
__global__ void k_score(Ptrs P, float* scoreAll, int* clsAll, float4* boxAll) {
    int p = blockIdx.x * blockDim.x + threadIdx.x;
    if (p >= NPOS) return;
    int img = blockIdx.y;
    int lvl, base, lw, stride;
    if (p < 16384)      { lvl = 0; base = 0;     lw = 7; stride = 8;   }
    else if (p < 20480) { lvl = 1; base = 16384; lw = 6; stride = 16;  }
    else if (p < 21504) { lvl = 2; base = 20480; lw = 5; stride = 32;  }
    else if (p < 21760) { lvl = 3; base = 21504; lw = 4; stride = 64;  }
    else                { lvl = 4; base = 21760; lw = 3; stride = 128; }
    int pl = p - base;
    int h = pl >> lw, w = pl & ((1 << lw) - 1);
    long long lidx = (long long)img * (1 << (2 * lw)) + pl;

    const float4* c4 = (const float4*)(P.cls[lvl] + lidx * 80);
    float mx = -3.4e38f; int mi = 0;
#pragma unroll
    for (int j = 0; j < 20; ++j) {
        float4 v = c4[j];
        if (v.x > mx) { mx = v.x; mi = 4 * j;     }
        if (v.y > mx) { mx = v.y; mi = 4 * j + 1; }
        if (v.z > mx) { mx = v.z; mi = 4 * j + 2; }
        if (v.w > mx) { mx = v.w; mi = 4 * j + 3; }
    }
    float ct = P.ctr[lvl][lidx];
    float sc = sqrtf(sigf(mx) * sigf(ct));   // sigmoid(max) == max(sigmoid)

    float4 rg = ((const float4*)P.reg[lvl])[lidx];
    float x = (w + 0.5f) * (float)stride;
    float y = (h + 0.5f) * (float)stride;
    int ix1 = (int)(x - expf(rg.x));
    int iy1 = (int)(y - expf(rg.y));
    int ix2 = (int)(x + expf(rg.z));
    int iy2 = (int)(y + expf(rg.w));
    ix1 = max(ix1, 0); iy1 = max(iy1, 0);
    ix2 = min(ix2, 1023); iy2 = min(iy2, 1023);

    int o = img * NPOS + p;
    scoreAll[o] = sc;
    clsAll[o]   = mi;
    boxAll[o]   = make_float4((float)ix1, (float)iy1, (float)ix2, (float)iy2);
}

// ------- Kernel B: exact k=1000 radix select per (image, level 0..2) --------
// Parallel suffix-scan crossing search (old version had ~6144 serial LDS reads).
__global__ __launch_bounds__(256) void k_select(const float* scoreAll, unsigned int* kth,
                                                int* eqcnt, int* eqidx, int* ccnt) {
    const int baseArr[3] = {0, 16384, 20480};
    const int NlArr[3]   = {16384, 4096, 1024};
    int il  = blockIdx.x;            // img*3 + lvl
    int img = il / 3, lvl = il % 3;
    int Nl  = NlArr[lvl];
    const unsigned int* sb = (const unsigned int*)scoreAll + img * NPOS + baseArr[lvl];

    __shared__ int hist[2048];
    __shared__ int partial[256];
    __shared__ unsigned int shPrefix;
    __shared__ int shK, listCnt;
    __shared__ int list[256];
    int tid = threadIdx.x;
    if (tid == 0) { shK = 1000; shPrefix = 0; listCnt = 0; ccnt[il] = 0; }
    __syncthreads();

    const int shifts[3]  = {21, 10, 0};
    const int nbArr[3]   = {2048, 2048, 1024};

    for (int pass = 0; pass < 3; ++pass) {
        int nb = nbArr[pass], sh = shifts[pass];
        int matchSh = sh + ((pass == 2) ? 10 : 11);
        unsigned int pref = shPrefix;
        int K = shK;

        for (int i = tid; i < 2048; i += 256) hist[i] = 0;
        __syncthreads();
        for (int i = tid; i < Nl; i += 256) {
            unsigned int b = sb[i];
            bool match = (pass == 0) || ((b >> matchSh) == (pref >> matchSh));
            if (match) atomicAdd(&hist[(b >> sh) & (nb - 1)], 1);
        }
        __syncthreads();

        // per-thread partial over its bin range, then inclusive suffix scan
        int g  = nb >> 8;
        int lo = tid * g;
        int lsum = 0;
        for (int q = 0; q < g; ++q) lsum += hist[lo + q];
        partial[tid] = lsum;
        __syncthreads();
        for (int off = 1; off < 256; off <<= 1) {
            int v = partial[tid];
            if (tid + off < 256) v += partial[tid + off];
            __syncthreads();
            partial[tid] = v;
            __syncthreads();
        }
        int mine  = partial[tid];
        int above = (tid < 255) ? partial[tid + 1] : 0;
        if (above < K && mine >= K) {       // exactly one thread
            int cum = above;
            for (int b = lo + g - 1; b >= lo; --b) {
                cum += hist[b];
                if (cum >= K) {
                    shPrefix = pref | ((unsigned int)b << sh);
                    shK = K - (cum - hist[b]);
                    break;
                }
            }
        }
        __syncthreads();
    }

    unsigned int kv = shPrefix;             // exact k-th value bits
    if (tid == 0) kth[il] = kv;
    // collect indices equal to kth; top_k keeps lowest-index ones
    for (int i = tid; i < Nl; i += 256) {
        if (sb[i] == kv) { int t = atomicAdd(&listCnt, 1); if (t < 256) list[t] = i; }
    }
    __syncthreads();
    if (tid == 0) {
        int m = min(listCnt, 256);
        for (int a = 1; a < m; ++a) {       // insertion sort ascending (m tiny)
            int v = list[a], b2 = a - 1;
            while (b2 >= 0 && list[b2] > v) { list[b2 + 1] = list[b2]; --b2; }
            list[b2 + 1] = v;
        }
        int take = min(shK, m);
        eqcnt[il] = take;
        for (int q = 0; q < take; ++q) eqidx[il * 256 + q] = list[q];
    }
}

// --------------- Kernel C: compact selected candidates to u64 keys ----------
// key = (score_bits << 15) | p   (p < 21824 < 2^15); slot order irrelevant.
__global__ void k_compact(const float* scoreAll, const unsigned int* kth,
                          const int* eqcnt, const int* eqidx, int* ccnt,
                          unsigned long long* cKey) {
    int p = blockIdx.x * blockDim.x + threadIdx.x;
    if (p >= NPOS) return;
    int img = blockIdx.y;
    int lvl, base, cbase;
    if (p < 16384)      { lvl = 0; base = 0;     cbase = 0;    }
    else if (p < 20480) { lvl = 1; base = 16384; cbase = 1000; }
    else if (p < 21504) { lvl = 2; base = 20480; cbase = 2000; }
    else if (p < 21760) { lvl = 3; base = 21504; cbase = 3000; }
    else                { lvl = 4; base = 21760; cbase = 3256; }
    int pl = p - base;
    int o  = img * NPOS + p;
    unsigned int bits = ((const unsigned int*)scoreAll)[o];
    int slot;
    if (lvl < 3) {
        int il = img * 3 + lvl;
        unsigned int kb = kth[il];
        bool sel = bits > kb;
        if (!sel && bits == kb) {
            int ec = eqcnt[il];
            for (int q = 0; q < ec; ++q)
                if (eqidx[il * 256 + q] == pl) { sel = true; break; }
        }
        if (!sel) return;
        slot = cbase + atomicAdd(&ccnt[il], 1);
    } else {
        slot = cbase + pl;
    }
    cKey[img * NC + slot] = ((unsigned long long)bits << 15) | (unsigned int)p;
}

// --------- Kernel D: per-image bitonic sort + greedy early-exit NMS ---------
__global__ __launch_bounds__(256) void k_nms(const unsigned long long* cKey,
                                             const float4* boxAll, const int* clsAll,
                                             float* out) {
    __shared__ unsigned long long key[4096];
    int img = blockIdx.x;
    int tid = threadIdx.x;

    for (int i = tid; i < 4096; i += 256)
        key[i] = (i < NC) ? cKey[img * NC + i] : 0ULL;

    float* outS = out + img * 100;
    float* outC = out + 800 + img * 100;
    float* outB = out + 1600 + img * 400;
    for (int i = tid; i < 100; i += 256) { outS[i] = -1.0f; outC[i] = -1.0f; }
    for (int i = tid; i < 400; i += 256) outB[i] = -1.0f;
    __syncthreads();

    // bitonic ascending sort of 4096 u64 keys (pads=0 sink to the bottom)
    for (int k = 2; k <= 4096; k <<= 1) {
        for (int j = k >> 1; j > 0; j >>= 1) {
            for (int i = tid; i < 4096; i += 256) {
                int ixj = i ^ j;
                if (ixj > i) {
                    unsigned long long a = key[i], b = key[ixj];
                    bool asc = ((i & k) == 0);
                    if ((a > b) == asc) { key[i] = b; key[ixj] = a; }
                }
            }
            __syncthreads();
        }
    }

    // greedy NMS on one wave; accepted boxes live 2-per-lane in registers
    if (tid < 64) {
        int lane = tid;
        float4 aB0 = make_float4(0,0,0,0), aB1 = make_float4(0,0,0,0);
        float  aA0 = 0.0f, aA1 = 0.0f;
        int na = 0;
        int i  = 4095;

        unsigned long long kk = key[i];
        int    p  = (int)(kk & 32767u);
        float4 bb = boxAll[img * NPOS + p];   // same addr all lanes -> broadcast

        while (na < 100 && kk != 0ULL) {
            float sc = __uint_as_float((unsigned int)(kk >> 15));
            if (!(sc > MINS)) break;
            float ba = (bb.z - bb.x) * (bb.w - bb.y);

            // prefetch next candidate while deciding current
            unsigned long long nk = (i > 0) ? key[i - 1] : 0ULL;
            int    np  = (int)(nk & 32767u);
            float4 nb_ = bb;
            if (nk != 0ULL) nb_ = boxAll[img * NPOS + np];

            bool sup = false;
            if (lane < na) {
                float iw = fmaxf(fminf(bb.z, aB0.z) - fmaxf(bb.x, aB0.x), 0.0f);
                float ih = fmaxf(fminf(bb.w, aB0.w) - fmaxf(bb.y, aB0.y), 0.0f);
                float inter = iw * ih;
                float iou = inter / (ba + aA0 - inter + 1e-12f);
                sup = iou > 0.6f;
            }
            if (lane + 64 < na) {
                float iw = fmaxf(fminf(bb.z, aB1.z) - fmaxf(bb.x, aB1.x), 0.0f);
                float ih = fmaxf(fminf(bb.w, aB1.w) - fmaxf(bb.y, aB1.y), 0.0f);
                float inter = iw * ih;
                float iou = inter / (ba + aA1 - inter + 1e-12f);
                sup = sup || (iou > 0.6f);
            }
            if (__ballot(sup) == 0ULL) {      // accept
                if (lane == 0) {
                    outS[na] = sc;
                    outC[na] = (float)clsAll[img * NPOS + p];
                    outB[4 * na + 0] = bb.x; outB[4 * na + 1] = bb.y;
                    outB[4 * na + 2] = bb.z; outB[4 * na + 3] = bb.w;
                }
                if (lane == (na & 63)) {
                    if (na < 64) { aB0 = bb; aA0 = ba; }
                    else         { aB1 = bb; aA1 = ba; }
                }
                ++na;
            }
            --i; kk = nk; p = np; bb = nb_;
        }
    }
}

extern "C" void kernel_launch(void* const* d_in, const int* in_sizes, int n_in,
                              void* d_out, int out_size, void* d_ws, size_t ws_size,
                              hipStream_t stream) {
    Ptrs P;
    bool interleaved = (in_sizes[1] == 8 * 128 * 128 * 4);
    for (int i = 0; i < 5; ++i) {
        if (interleaved) {
            P.cls[i] = (const float*)d_in[3 * i];
            P.reg[i] = (const float*)d_in[3 * i + 1];
            P.ctr[i] = (const float*)d_in[3 * i + 2];
        } else {
            P.cls[i] = (const float*)d_in[i];
            P.reg[i] = (const float*)d_in[5 + i];
            P.ctr[i] = (const float*)d_in[10 + i];
        }
    }

    char* wbase = (char*)d_ws;
    size_t off = 0;
    auto alloc = [&](size_t bytes) -> void* {
        void* r = wbase + off;
        off += (bytes + 255) & ~(size_t)255;
        return r;
    };
    float*              scoreAll = (float*)alloc((size_t)8 * NPOS * 4);
    int*                clsAll   = (int*)alloc((size_t)8 * NPOS * 4);
    float4*             boxAll   = (float4*)alloc((size_t)8 * NPOS * 16);
    unsigned int*       kth      = (unsigned int*)alloc(24 * 4);
    int*                eqcnt    = (int*)alloc(24 * 4);
    int*                eqidx    = (int*)alloc(24 * 256 * 4);
    int*                ccnt     = (int*)alloc(24 * 4);
    unsigned long long* cKey     = (unsigned long long*)alloc((size_t)8 * NC * 8);

    dim3 gA((NPOS + 255) / 256, 8);
    k_score  <<<gA, 256, 0, stream>>>(P, scoreAll, clsAll, boxAll);
    k_select <<<24, 256, 0, stream>>>(scoreAll, kth, eqcnt, eqidx, ccnt);
    k_compact<<<gA, 256, 0, stream>>>(scoreAll, kth, eqcnt, eqidx, ccnt, cKey);
    k_nms    <<<8, 256, 0, stream>>>(cKey, boxAll, clsAll, (float*)d_out);
}

// Round 3
// 269.031 us; speedup vs baseline: 3.9233x; 2.0687x over previous
//
#include <hip/hip_runtime.h>

#define NPOS 21824          // 16384+4096+1024+256+64 positions per image
#define NC   3320           // 1000+1000+1000+256+64 candidates per image
#define MINS 0.05f

struct Ptrs { const float* cls[5]; const float* reg[5]; const float* ctr[5]; };

__device__ __forceinline__ float sigf(float x){ return 1.0f/(1.0f+expf(-x)); }

// ---------------- Kernel A: score / class / box, 4 lanes per position -------
// Block = 256 threads = 64 positions. All level boundaries are multiples of 64
// so the level is block-uniform. Lane l of a 4-lane group reads float4 #l,
// #4+l, #8+l, ... -> each 64B line is fully consumed by its 4 lanes.
__global__ __launch_bounds__(256) void k_score(Ptrs P, float* scoreAll, int* clsAll,
                                               float4* boxAll)
{
    int img  = blockIdx.y;
    int blk  = blockIdx.x;           // [0,341)
    int tid  = threadIdx.x;
    int posb = tid >> 2;             // position within block [0,64)
    int l    = tid & 3;              // lane within 4-lane group
    int p    = blk*64 + posb;
    int lvl, base, lw, stride;
    if (blk < 256)      { lvl=0; base=0;     lw=7; stride=8;   }
    else if (blk < 320) { lvl=1; base=16384; lw=6; stride=16;  }
    else if (blk < 336) { lvl=2; base=20480; lw=5; stride=32;  }
    else if (blk < 340) { lvl=3; base=21504; lw=4; stride=64;  }
    else                { lvl=4; base=21760; lw=3; stride=128; }
    int pl = p - base;
    int h = pl >> lw, w = pl & ((1<<lw)-1);
    long long lidx = (long long)img*(1<<(2*lw)) + pl;

    const float4* c4 = (const float4*)(P.cls[lvl] + lidx*80);
    float mx = -3.4e38f; int mi = 0;
#pragma unroll
    for (int j = 0; j < 5; ++j) {
        int k = j*4 + l;
        float4 v = c4[k];
        int cb = k*4;
        if (v.x > mx){mx=v.x; mi=cb;}
        if (v.y > mx){mx=v.y; mi=cb+1;}
        if (v.z > mx){mx=v.z; mi=cb+2;}
        if (v.w > mx){mx=v.w; mi=cb+3;}
    }
    // merge across 4-lane group; first-occurrence (lowest class index) on ties
#pragma unroll
    for (int d = 1; d < 4; d <<= 1) {
        float omx = __shfl_xor(mx, d);
        int   omi = __shfl_xor(mi, d);
        if (omx > mx || (omx == mx && omi < mi)) { mx = omx; mi = omi; }
    }
    if (l == 0) {
        float ct = P.ctr[lvl][lidx];
        float sc = sqrtf(sigf(mx)*sigf(ct));   // sigmoid(max)==max(sigmoid)
        float4 rg = ((const float4*)P.reg[lvl])[lidx];
        float x = (w + 0.5f)*(float)stride;
        float y = (h + 0.5f)*(float)stride;
        int ix1 = (int)(x - expf(rg.x));
        int iy1 = (int)(y - expf(rg.y));
        int ix2 = (int)(x + expf(rg.z));
        int iy2 = (int)(y + expf(rg.w));
        ix1 = max(ix1,0); iy1 = max(iy1,0);
        ix2 = min(ix2,1023); iy2 = min(iy2,1023);
        int o = img*NPOS + p;
        scoreAll[o] = sc;
        clsAll[o]   = mi;
        boxAll[o]   = make_float4((float)ix1,(float)iy1,(float)ix2,(float)iy2);
    }
}

// ---- exact K-th-largest u32 via 3-pass radix + parallel suffix scan --------
// vals may be global or LDS. On return *shPrefix = kth value, *shK = #needed
// among equals (>=1). Must be called by all 256 threads.
__device__ void radix_select(const unsigned int* vals, int N, int K,
                             int* hist, int* partial,
                             unsigned int* shPrefix, int* shK, int tid)
{
    if (tid == 0) { *shPrefix = 0; *shK = K; }
    __syncthreads();
    const int shifts[3] = {21, 10, 0};
    const int nbs[3]    = {2048, 2048, 1024};
    for (int pass = 0; pass < 3; ++pass) {
        int nb = nbs[pass], sh = shifts[pass];
        int matchSh = sh + ((pass == 2) ? 10 : 11);
        unsigned int pref = *shPrefix;
        int K2 = *shK;
        for (int i = tid; i < 2048; i += 256) hist[i] = 0;
        __syncthreads();
#pragma unroll 4
        for (int i = tid; i < N; i += 256) {
            unsigned int b = vals[i];
            bool match = (pass == 0) || ((b >> matchSh) == (pref >> matchSh));
            if (match) atomicAdd(&hist[(b >> sh) & (nb-1)], 1);
        }
        __syncthreads();
        int g = nb >> 8, lo = tid*g, ls = 0;
        for (int q = 0; q < g; ++q) ls += hist[lo+q];
        partial[tid] = ls;
        __syncthreads();
        for (int off = 1; off < 256; off <<= 1) {
            int v = partial[tid];
            if (tid + off < 256) v += partial[tid+off];
            __syncthreads();
            partial[tid] = v;
            __syncthreads();
        }
        int mine  = partial[tid];
        int above = (tid < 255) ? partial[tid+1] : 0;
        if (above < K2 && mine >= K2) {          // exactly one thread
            int cum = above;
            for (int b = lo+g-1; b >= lo; --b) {
                cum += hist[b];
                if (cum >= K2) { *shPrefix = pref | ((unsigned int)b << sh);
                                 *shK = K2 - (cum - hist[b]); break; }
            }
        }
        __syncthreads();
    }
}

// ------- Kernel B: fused per-image top-k + rank + greedy NMS (8 blocks) -----
// key = (score_bits << 16) | (65535 - p): descending key order == descending
// score with ties broken by LOWER p (== reference concat order). Keys unique.
__global__ __launch_bounds__(256) void k_fused(const float* scoreAll, const int* clsAll,
                                               const float4* boxAll,
                                               unsigned long long* cKeyG, float* out)
{
    __shared__ __align__(16) unsigned char smem[61408];
    unsigned long long* cand = (unsigned long long*)smem;            // [3320] 0..26560
    unsigned int* cbits = (unsigned int*)(smem + 26560);             // [3320] ..39840
    int* hist    = (int*)(smem + 39840);                             // [2048] ..48032
    int* partial = (int*)(smem + 48032);                             // [256]  ..49056
    int* eqlist  = (int*)(smem + 49056);                             // [1024] ..53152
    unsigned long long* sel = (unsigned long long*)(smem + 53152);   // [1024] ..61344
    unsigned int* shKth = (unsigned int*)(smem + 61344);
    int* shNeed  = (int*)(smem + 61348);
    int* shTick  = (int*)(smem + 61352);
    int* shEqN   = (int*)(smem + 61356);
    // phase-C overlay (cand/cbits dead by then):
    unsigned long long* sorted = (unsigned long long*)smem;          // [1024] 0..8192
    float4* sBox = (float4*)(smem + 8192);                           // [1024] ..24576
    float*  sCls = (float*)(smem + 24576);                           // [1024] ..28672

    int img = blockIdx.x, tid = threadIdx.x;
    const unsigned int* gs = (const unsigned int*)scoreAll + (long long)img*NPOS;
    const float4* gBox = boxAll + (long long)img*NPOS;
    const int*    gCls = clsAll + (long long)img*NPOS;
    unsigned long long* gKey = cKeyG + (long long)img*NC;

    float* outS = out + img*100;
    float* outC = out + 800 + img*100;
    float* outB = out + 1600 + img*400;
    for (int i = tid; i < 100; i += 256){ outS[i] = -1.f; outC[i] = -1.f; }
    for (int i = tid; i < 400; i += 256) outB[i] = -1.f;

    const int baseArr[3]  = {0, 16384, 20480};
    const int NlArr[3]    = {16384, 4096, 1024};
    const int cbaseArr[3] = {0, 1000, 2000};

    // ---- phase A: per-level exact top-1000 -> cand[0..3000) ----
    for (int lvl = 0; lvl < 3; ++lvl) {
        int base = baseArr[lvl], Nl = NlArr[lvl];
        radix_select(gs + base, Nl, 1000, hist, partial, shKth, shNeed, tid);
        if (tid == 0) { *shTick = cbaseArr[lvl]; *shEqN = 0; }
        __syncthreads();
        unsigned int kth = *shKth;
#pragma unroll 4
        for (int i = tid; i < Nl; i += 256) {
            unsigned int b = gs[base+i];
            if (b > kth) {
                int t = atomicAdd(shTick, 1);
                int p = base + i;
                unsigned long long k = ((unsigned long long)b << 16) | (unsigned)(65535 - p);
                cand[t] = k; gKey[t] = k;
            } else if (b == kth) {
                int t = atomicAdd(shEqN, 1);
                if (t < 1024) eqlist[t] = i;
            }
        }
        __syncthreads();
        if (tid == 0) {
            int need = *shNeed, m = *shEqN, tk = *shTick;
            if (m <= 1024) {
                for (int a = 1; a < m; ++a) {           // ascending (tiny)
                    int v = eqlist[a], b2 = a-1;
                    while (b2 >= 0 && eqlist[b2] > v){ eqlist[b2+1]=eqlist[b2]; --b2; }
                    eqlist[b2+1] = v;
                }
                for (int q = 0; q < need; ++q) {
                    int p = base + eqlist[q];
                    unsigned long long k = ((unsigned long long)kth << 16) | (unsigned)(65535 - p);
                    cand[tk] = k; gKey[tk] = k; ++tk;
                }
            } else {                                    // overflow fallback (rare)
                int cnt = 0;
                for (int i = 0; i < Nl && cnt < need; ++i)
                    if (gs[base+i] == kth) {
                        int p = base + i;
                        unsigned long long k = ((unsigned long long)kth << 16) | (unsigned)(65535 - p);
                        cand[tk] = k; gKey[tk] = k; ++tk; ++cnt;
                    }
            }
        }
        __syncthreads();
    }
    // levels 3,4: all positions -> cand[3000..3320)
    for (int i = tid; i < 320; i += 256) {
        int p = 21504 + i;
        unsigned long long k = ((unsigned long long)gs[p] << 16) | (unsigned)(65535 - p);
        cand[3000 + i] = k; gKey[3000 + i] = k;
    }
    __syncthreads();

    // ---- phase B: exact top-1024 of cand -> sel[1024] ----
    for (int i = tid; i < NC; i += 256) cbits[i] = (unsigned int)(cand[i] >> 16);
    __syncthreads();
    radix_select(cbits, NC, 1024, hist, partial, shKth, shNeed, tid);
    if (tid == 0) { *shTick = 0; *shEqN = 0; }
    __syncthreads();
    unsigned int kth2 = *shKth;
    for (int i = tid; i < NC; i += 256) {
        unsigned int b = cbits[i];
        if (b > kth2)      { int t = atomicAdd(shTick, 1); sel[t] = cand[i]; }
        else if (b == kth2){ int t = atomicAdd(shEqN, 1); if (t < 1024) eqlist[t] = i; }
    }
    __syncthreads();
    if (tid == 0) {
        int need = *shNeed, m = *shEqN, tk = *shTick;
        if (m <= 1024) {
            for (int a = 1; a < m; ++a) {               // by key DESC (lower p first)
                int v = eqlist[a]; unsigned long long kv = cand[v]; int b2 = a-1;
                while (b2 >= 0 && cand[eqlist[b2]] < kv){ eqlist[b2+1]=eqlist[b2]; --b2; }
                eqlist[b2+1] = v;
            }
            for (int q = 0; q < need; ++q) sel[tk++] = cand[eqlist[q]];
        } else {                                        // rare serial path
            unsigned long long last = ~0ULL;
            for (int q = 0; q < need; ++q) {
                unsigned long long best = 0;
                for (int i = 0; i < NC; ++i) {
                    unsigned long long k = cand[i];
                    if ((unsigned int)(k >> 16) == kth2 && k < last && k > best) best = k;
                }
                sel[tk++] = best; last = best;
            }
        }
    }
    __syncthreads();

    // ---- phase C: rank-by-counting (keys unique -> unique ranks) ----
    unsigned long long mk0 = sel[tid], mk1 = sel[tid+256],
                       mk2 = sel[tid+512], mk3 = sel[tid+768];
    int r0 = 0, r1 = 0, r2 = 0, r3 = 0;
    for (int j = 0; j < 1024; ++j) {
        unsigned long long v = sel[j];                  // broadcast LDS read
        r0 += (v > mk0); r1 += (v > mk1); r2 += (v > mk2); r3 += (v > mk3);
    }
    __syncthreads();                                    // cand/cbits now dead
    sorted[r0] = mk0; sorted[r1] = mk1; sorted[r2] = mk2; sorted[r3] = mk3;
    __syncthreads();
    for (int i = tid; i < 1024; i += 256) {
        int p = 65535 - (int)(sorted[i] & 0xFFFF);
        sBox[i] = gBox[p];
        sCls[i] = (float)gCls[p];
    }
    __syncthreads();

    // ---- phase D: greedy early-exit walk, wave 0, LDS-only critical path ----
    if (tid < 64) {
        int lane = tid;
        float4 aB0 = make_float4(0,0,0,0), aB1 = make_float4(0,0,0,0);
        float  aA0 = 0.f, aA1 = 0.f;
        int na = 0;
        unsigned long long kk = sorted[0];
        float4 bb = sBox[0];
        float lastSc = 1e9f;
        int i = 0;
        for (; i < 1024 && na < 100; ++i) {
            float sc = __uint_as_float((unsigned int)(kk >> 16));
            lastSc = sc;
            if (!(sc > MINS)) break;
            unsigned long long nk = (i+1 < 1024) ? sorted[i+1] : 0ULL;  // prefetch
            float4 nb = (i+1 < 1024) ? sBox[i+1] : bb;
            float ba = (bb.z-bb.x)*(bb.w-bb.y);
            bool sup = false;
            if (lane < na) {
                float iw = fmaxf(fminf(bb.z,aB0.z)-fmaxf(bb.x,aB0.x),0.f);
                float ih = fmaxf(fminf(bb.w,aB0.w)-fmaxf(bb.y,aB0.y),0.f);
                float in_ = iw*ih;
                sup = in_/(ba+aA0-in_+1e-12f) > 0.6f;
            }
            if (lane + 64 < na) {
                float iw = fmaxf(fminf(bb.z,aB1.z)-fmaxf(bb.x,aB1.x),0.f);
                float ih = fmaxf(fminf(bb.w,aB1.w)-fmaxf(bb.y,aB1.y),0.f);
                float in_ = iw*ih;
                sup = sup || (in_/(ba+aA1-in_+1e-12f) > 0.6f);
            }
            if (__ballot(sup) == 0ULL) {
                if (lane == 0) {
                    outS[na] = sc;
                    outC[na] = sCls[i];
                    outB[4*na+0]=bb.x; outB[4*na+1]=bb.y;
                    outB[4*na+2]=bb.z; outB[4*na+3]=bb.w;
                }
                if (lane == (na & 63)) {
                    if (na < 64) { aB0 = bb; aA0 = ba; }
                    else         { aB1 = bb; aA1 = ba; }
                }
                ++na;
            }
            kk = nk; bb = nb;
        }

        // fallback: top-1024 exhausted before 100 accepted (never on real data)
        if (na < 100 && lastSc > MINS && i >= 1024) {
            unsigned long long thr = sorted[1023];
            unsigned long long* rem = (unsigned long long*)(smem + 8192); // sBox dead
            for (int j = lane; j < NC; j += 64) {
                unsigned long long v = gKey[j];
                rem[j] = (v >= thr) ? 0ULL : v;        // top-1024 already consumed
            }
            __threadfence_block();
            while (na < 100) {
                unsigned long long bk = 0; int bidx = -1;
                for (int j = lane; j < NC; j += 64) {
                    unsigned long long v = rem[j];
                    if (v > bk) { bk = v; bidx = j; }
                }
#pragma unroll
                for (int off = 32; off > 0; off >>= 1) {
                    unsigned long long ov = __shfl_down(bk, off);
                    int oi = __shfl_down(bidx, off);
                    if (ov > bk) { bk = ov; bidx = oi; }
                }
                bk = __shfl(bk, 0); bidx = __shfl(bidx, 0);
                if (bk == 0ULL) break;
                float sc = __uint_as_float((unsigned int)(bk >> 16));
                if (!(sc > MINS)) break;
                int p = 65535 - (int)(bk & 0xFFFF);
                float4 bb2 = gBox[p];
                float ba = (bb2.z-bb2.x)*(bb2.w-bb2.y);
                bool sup = false;
                if (lane < na) {
                    float iw = fmaxf(fminf(bb2.z,aB0.z)-fmaxf(bb2.x,aB0.x),0.f);
                    float ih = fmaxf(fminf(bb2.w,aB0.w)-fmaxf(bb2.y,aB0.y),0.f);
                    float in_ = iw*ih;
                    sup = in_/(ba+aA0-in_+1e-12f) > 0.6f;
                }
                if (lane + 64 < na) {
                    float iw = fmaxf(fminf(bb2.z,aB1.z)-fmaxf(bb2.x,aB1.x),0.f);
                    float ih = fmaxf(fminf(bb2.w,aB1.w)-fmaxf(bb2.y,aB1.y),0.f);
                    float in_ = iw*ih;
                    sup = sup || (in_/(ba+aA1-in_+1e-12f) > 0.6f);
                }
                if (__ballot(sup) == 0ULL) {
                    if (lane == 0) {
                        outS[na] = sc;
                        outC[na] = (float)gCls[p];
                        outB[4*na+0]=bb2.x; outB[4*na+1]=bb2.y;
                        outB[4*na+2]=bb2.z; outB[4*na+3]=bb2.w;
                    }
                    if (lane == (na & 63)) {
                        if (na < 64) { aB0 = bb2; aA0 = ba; }
                        else         { aB1 = bb2; aA1 = ba; }
                    }
                    ++na;
                }
                if (lane == 0) rem[bidx] = 0ULL;
                __threadfence_block();
            }
        }
    }
}

extern "C" void kernel_launch(void* const* d_in, const int* in_sizes, int n_in,
                              void* d_out, int out_size, void* d_ws, size_t ws_size,
                              hipStream_t stream) {
    Ptrs P;
    bool interleaved = (in_sizes[1] == 8 * 128 * 128 * 4);
    for (int i = 0; i < 5; ++i) {
        if (interleaved) {
            P.cls[i] = (const float*)d_in[3*i];
            P.reg[i] = (const float*)d_in[3*i + 1];
            P.ctr[i] = (const float*)d_in[3*i + 2];
        } else {
            P.cls[i] = (const float*)d_in[i];
            P.reg[i] = (const float*)d_in[5 + i];
            P.ctr[i] = (const float*)d_in[10 + i];
        }
    }

    char* wbase = (char*)d_ws;
    size_t off = 0;
    auto alloc = [&](size_t bytes) -> void* {
        void* r = wbase + off;
        off += (bytes + 255) & ~(size_t)255;
        return r;
    };
    float*              scoreAll = (float*)alloc((size_t)8 * NPOS * 4);
    int*                clsAll   = (int*)alloc((size_t)8 * NPOS * 4);
    float4*             boxAll   = (float4*)alloc((size_t)8 * NPOS * 16);
    unsigned long long* cKeyG    = (unsigned long long*)alloc((size_t)8 * NC * 8);

    dim3 gA(341, 8);   // 341*64 = 21824 positions, level boundaries block-aligned
    k_score<<<gA, 256, 0, stream>>>(P, scoreAll, clsAll, boxAll);
    k_fused<<<8, 256, 0, stream>>>(scoreAll, clsAll, boxAll, cKeyG, (float*)d_out);
}

// Round 4
// 219.481 us; speedup vs baseline: 4.8090x; 1.2258x over previous
//
#include <hip/hip_runtime.h>

#define NPOS 21824          // 16384+4096+1024+256+64 positions per image
#define NC   3320           // 1000+1000+1000+256+64 candidates per image
#define MINS 0.05f

struct Ptrs { const float* cls[5]; const float* reg[5]; const float* ctr[5]; };

__device__ __forceinline__ float sigf(float x){ return 1.0f/(1.0f+expf(-x)); }

// ---------------- Kernel A: score / class / box, 4 lanes per position -------
__global__ __launch_bounds__(256) void k_score(Ptrs P, float* scoreAll, int* clsAll,
                                               float4* boxAll)
{
    int img  = blockIdx.y;
    int blk  = blockIdx.x;           // [0,341)
    int tid  = threadIdx.x;
    int posb = tid >> 2;             // position within block [0,64)
    int l    = tid & 3;              // lane within 4-lane group
    int p    = blk*64 + posb;
    int lvl, base, lw, stride;
    if (blk < 256)      { lvl=0; base=0;     lw=7; stride=8;   }
    else if (blk < 320) { lvl=1; base=16384; lw=6; stride=16;  }
    else if (blk < 336) { lvl=2; base=20480; lw=5; stride=32;  }
    else if (blk < 340) { lvl=3; base=21504; lw=4; stride=64;  }
    else                { lvl=4; base=21760; lw=3; stride=128; }
    int pl = p - base;
    int h = pl >> lw, w = pl & ((1<<lw)-1);
    long long lidx = (long long)img*(1<<(2*lw)) + pl;

    const float4* c4 = (const float4*)(P.cls[lvl] + lidx*80);
    float mx = -3.4e38f; int mi = 0;
#pragma unroll
    for (int j = 0; j < 5; ++j) {
        int k = j*4 + l;
        float4 v = c4[k];
        int cb = k*4;
        if (v.x > mx){mx=v.x; mi=cb;}
        if (v.y > mx){mx=v.y; mi=cb+1;}
        if (v.z > mx){mx=v.z; mi=cb+2;}
        if (v.w > mx){mx=v.w; mi=cb+3;}
    }
#pragma unroll
    for (int d = 1; d < 4; d <<= 1) {
        float omx = __shfl_xor(mx, d);
        int   omi = __shfl_xor(mi, d);
        if (omx > mx || (omx == mx && omi < mi)) { mx = omx; mi = omi; }
    }
    if (l == 0) {
        float ct = P.ctr[lvl][lidx];
        float sc = sqrtf(sigf(mx)*sigf(ct));   // sigmoid(max)==max(sigmoid)
        float4 rg = ((const float4*)P.reg[lvl])[lidx];
        float x = (w + 0.5f)*(float)stride;
        float y = (h + 0.5f)*(float)stride;
        int ix1 = (int)(x - expf(rg.x));
        int iy1 = (int)(y - expf(rg.y));
        int ix2 = (int)(x + expf(rg.z));
        int iy2 = (int)(y + expf(rg.w));
        ix1 = max(ix1,0); iy1 = max(iy1,0);
        ix2 = min(ix2,1023); iy2 = min(iy2,1023);
        int o = img*NPOS + p;
        scoreAll[o] = sc;
        clsAll[o]   = mi;
        boxAll[o]   = make_float4((float)ix1,(float)iy1,(float)ix2,(float)iy2);
    }
}

// ---- exact K-th-largest u32, 3-pass radix (19/8/0), wave suffix scan -------
// Monotone bins: scores are positive floats < 2.0 -> bits>>19 < 2048.
__device__ void radix_sel(const unsigned int* vals, int N, int K,
                          int* hist, int* wsum, unsigned int* shPref, int* shK,
                          int tid)
{
    if (tid == 0) { *shPref = 0; *shK = K; }
    __syncthreads();
    const int shv[3] = {19, 8, 0};
    const int nbv[3] = {2048, 2048, 256};
    for (int pass = 0; pass < 3; ++pass) {
        int sh = shv[pass], nb = nbv[pass];
        unsigned int pref = *shPref;
        int K2 = *shK;
        for (int i = tid; i < nb; i += 256) hist[i] = 0;
        __syncthreads();
#pragma unroll 4
        for (int i = tid; i < N; i += 256) {
            unsigned int b = vals[i];
            bool match = (pass == 0) ||
                         (pass == 1 ? ((b >> 19) == (pref >> 19))
                                    : ((b >> 8)  == (pref >> 8)));
            if (match) atomicAdd(&hist[(b >> sh) & (nb - 1)], 1);
        }
        __syncthreads();
        int g = nb >> 8, lo = tid * g, ls = 0;
        for (int q = 0; q < g; ++q) ls += hist[lo + q];
        int lane = tid & 63, wv = tid >> 6;
        int v = ls;
#pragma unroll
        for (int off = 1; off < 64; off <<= 1) {
            int o = __shfl_down(v, off);
            if (lane + off < 64) v += o;
        }
        if (lane == 0) wsum[wv] = v;     // wave total (lane0 suffix = whole wave)
        __syncthreads();
        int add = 0;
        for (int q = wv + 1; q < 4; ++q) add += wsum[q];
        int mine = v + add;              // suffix sum threads [tid..255]
        int above = mine - ls;           // suffix sum threads (tid..255]
        if (above < K2 && mine >= K2) {  // exactly one thread crosses
            int cum = above;
            for (int b = lo + g - 1; b >= lo; --b) {
                cum += hist[b];
                if (cum >= K2) {
                    *shPref = pref | ((unsigned int)b << sh);
                    *shK = K2 - (cum - hist[b]);
                    break;
                }
            }
        }
        __syncthreads();
    }
}

// --- Kernel B: per-(img,lvl) exact top-1000 -> cKeyG (32 blocks parallel) ---
// key = (score_bits<<16) | (65535-p): desc key == desc score, ties lower p.
__global__ __launch_bounds__(256) void k_thresh(const float* scoreAll,
                                                unsigned long long* cKeyG)
{
    __shared__ int hist[2048];
    __shared__ int wsum[4];
    __shared__ unsigned int shPref;
    __shared__ int shK, tick, eqn;
    __shared__ int eq[1024];
    int il = blockIdx.x, tid = threadIdx.x;

    if (il >= 24) {                      // blocks 24..31: levels 3+4 copier
        int img = il - 24;
        const unsigned int* gs = (const unsigned int*)scoreAll + (long long)img*NPOS;
        unsigned long long* gk = cKeyG + (long long)img*NC;
        for (int i = tid; i < 320; i += 256) {
            int p = 21504 + i;
            gk[3000 + i] = ((unsigned long long)gs[p] << 16) | (unsigned)(65535 - p);
        }
        return;
    }
    int img = il / 3, lvl = il % 3;
    const int baseA[3] = {0, 16384, 20480};
    const int NlA[3]   = {16384, 4096, 1024};
    const int cbA[3]   = {0, 1000, 2000};
    int base = baseA[lvl], Nl = NlA[lvl];
    const unsigned int* gs = (const unsigned int*)scoreAll + (long long)img*NPOS + base;
    unsigned long long* gk = cKeyG + (long long)img*NC + cbA[lvl];

    radix_sel(gs, Nl, 1000, hist, wsum, &shPref, &shK, tid);
    if (tid == 0) { tick = 0; eqn = 0; }
    __syncthreads();
    unsigned int kth = shPref;
    int need = shK;                      // #ties to keep (>=1)
#pragma unroll 4
    for (int i = tid; i < Nl; i += 256) {
        unsigned int b = gs[i];
        if (b > kth) {
            int t = atomicAdd(&tick, 1);
            int p = base + i;
            gk[t] = ((unsigned long long)b << 16) | (unsigned)(65535 - p);
        } else if (b == kth) {
            int t = atomicAdd(&eqn, 1);
            if (t < 1024) eq[t] = i;
        }
    }
    __syncthreads();
    int m = eqn, nG = tick;              // nG == 1000-need
    if (m <= 1024) {                     // keep the `need` LOWEST tie indices
        for (int q = tid; q < m; q += 256) {
            int iq = eq[q], r = 0;
            for (int j = 0; j < m; ++j) r += (eq[j] < iq);
            if (r < need) {
                int p = base + iq;
                gk[nG + r] = ((unsigned long long)kth << 16) | (unsigned)(65535 - p);
            }
        }
    } else if (tid == 0) {               // unreachable-in-practice fallback
        int cnt = 0;
        for (int i = 0; i < Nl && cnt < need; ++i)
            if (gs[i] == kth) {
                int p = base + i;
                gk[nG + cnt] = ((unsigned long long)kth << 16) | (unsigned)(65535 - p);
                ++cnt;
            }
    }
}

// ------ Kernel C: top-256 select + rank + greedy NMS walk (8 blocks) --------
__global__ __launch_bounds__(256) void k_nms2(const unsigned long long* cKeyG,
                                              const float4* boxAll, const int* clsAll,
                                              float* out)
{
    __shared__ unsigned long long cand[NC];
    __shared__ unsigned int cbits[NC];
    __shared__ int hist[2048];
    __shared__ int wsum[4];
    __shared__ unsigned int shPref;
    __shared__ int shK, tick, eqn;
    __shared__ int eq[256];
    __shared__ unsigned long long sel[256];
    __shared__ unsigned long long sorted[256];
    __shared__ float4 sBox[256];
    __shared__ float  sCls[256];

    int img = blockIdx.x, tid = threadIdx.x;
    const float4* gBox = boxAll + (long long)img*NPOS;
    const int*    gCls = clsAll + (long long)img*NPOS;
    const unsigned long long* gKey = cKeyG + (long long)img*NC;

    float* outS = out + img*100;
    float* outC = out + 800 + img*100;
    float* outB = out + 1600 + img*400;
    for (int i = tid; i < 100; i += 256){ outS[i] = -1.f; outC[i] = -1.f; }
    for (int i = tid; i < 400; i += 256) outB[i] = -1.f;

    for (int i = tid; i < NC; i += 256) {
        unsigned long long k = gKey[i];
        cand[i]  = k;
        cbits[i] = (unsigned int)(k >> 16);
    }
    __syncthreads();

    radix_sel(cbits, NC, 256, hist, wsum, &shPref, &shK, tid);
    if (tid == 0) { tick = 0; eqn = 0; }
    __syncthreads();
    unsigned int kth2 = shPref;
    int need2 = shK;
    for (int i = tid; i < NC; i += 256) {
        unsigned int b = cbits[i];
        if (b > kth2)       { int t = atomicAdd(&tick, 1); sel[t] = cand[i]; }
        else if (b == kth2) { int t = atomicAdd(&eqn, 1); if (t < 256) eq[t] = i; }
    }
    __syncthreads();
    int m2 = eqn, nG2 = tick;            // nG2 == 256-need2
    if (m2 <= 256) {                     // keep `need2` LARGEST keys among ties
        for (int q = tid; q < m2; q += 256) {
            unsigned long long kq = cand[eq[q]];
            int r = 0;
            for (int j = 0; j < m2; ++j) r += (cand[eq[j]] > kq);
            if (r < need2) sel[nG2 + r] = kq;
        }
    } else if (tid == 0) {               // unreachable-in-practice fallback
        unsigned long long last = ~0ULL;
        for (int c = 0; c < need2; ++c) {
            unsigned long long best = 0;
            for (int i = 0; i < NC; ++i) {
                unsigned long long k = cand[i];
                if ((unsigned int)(k >> 16) == kth2 && k < last && k > best) best = k;
            }
            sel[nG2 + c] = best; last = best;
        }
    }
    __syncthreads();

    // rank 256 unique keys by counting (1 key/thread, broadcast LDS reads)
    if (tid < 256) {
        unsigned long long k = sel[tid];
        int r = 0;
        for (int j = 0; j < 256; ++j) r += (sel[j] > k);
        sorted[r] = k;
    }
    __syncthreads();
    if (tid < 256) {
        int p = 65535 - (int)(sorted[tid] & 0xFFFF);
        sBox[tid] = gBox[p];
        sCls[tid] = (float)gCls[p];
    }
    __syncthreads();

    // greedy early-exit walk on wave 0; accepted boxes 2-per-lane in registers
    if (tid < 64) {
        int lane = tid;
        float4 aB0 = make_float4(0,0,0,0), aB1 = make_float4(0,0,0,0);
        float  aA0 = 0.f, aA1 = 0.f;
        int na = 0;
        unsigned long long kk = sorted[0];
        float4 bb = sBox[0];
        float lastSc = 1e9f;
        int i = 0;
        for (; i < 256 && na < 100; ++i) {
            float sc = __uint_as_float((unsigned int)(kk >> 16));
            lastSc = sc;
            if (!(sc > MINS)) break;
            unsigned long long nk = (i+1 < 256) ? sorted[i+1] : 0ULL;  // prefetch
            float4 nb = (i+1 < 256) ? sBox[i+1] : bb;
            float ba = (bb.z-bb.x)*(bb.w-bb.y);
            bool sup = false;
            if (lane < na) {
                float iw = fmaxf(fminf(bb.z,aB0.z)-fmaxf(bb.x,aB0.x),0.f);
                float ih = fmaxf(fminf(bb.w,aB0.w)-fmaxf(bb.y,aB0.y),0.f);
                float in_ = iw*ih;
                sup = in_/(ba+aA0-in_+1e-12f) > 0.6f;
            }
            if (lane + 64 < na) {
                float iw = fmaxf(fminf(bb.z,aB1.z)-fmaxf(bb.x,aB1.x),0.f);
                float ih = fmaxf(fminf(bb.w,aB1.w)-fmaxf(bb.y,aB1.y),0.f);
                float in_ = iw*ih;
                sup = sup || (in_/(ba+aA1-in_+1e-12f) > 0.6f);
            }
            if (__ballot(sup) == 0ULL) {
                if (lane == 0) {
                    outS[na] = sc;
                    outC[na] = sCls[i];
                    outB[4*na+0]=bb.x; outB[4*na+1]=bb.y;
                    outB[4*na+2]=bb.z; outB[4*na+3]=bb.w;
                }
                if (lane == (na & 63)) {
                    if (na < 64) { aB0 = bb; aA0 = ba; }
                    else         { aB1 = bb; aA1 = ba; }
                }
                ++na;
            }
            kk = nk; bb = nb;
        }

        // fallback: top-256 exhausted before 100 accepted (never on real data)
        if (na < 100 && lastSc > MINS && i >= 256) {
            unsigned long long thr = sorted[255];
            for (int j = lane; j < NC; j += 64)
                if (cand[j] >= thr) cand[j] = 0ULL;    // already consumed
            __threadfence_block();
            while (na < 100) {
                unsigned long long bk = 0; int bidx = -1;
                for (int j = lane; j < NC; j += 64) {
                    unsigned long long v = cand[j];
                    if (v > bk) { bk = v; bidx = j; }
                }
#pragma unroll
                for (int off = 32; off > 0; off >>= 1) {
                    unsigned long long ov = __shfl_down(bk, off);
                    int oi = __shfl_down(bidx, off);
                    if (ov > bk) { bk = ov; bidx = oi; }
                }
                bk = __shfl(bk, 0); bidx = __shfl(bidx, 0);
                if (bk == 0ULL) break;
                float sc = __uint_as_float((unsigned int)(bk >> 16));
                if (!(sc > MINS)) break;
                int p = 65535 - (int)(bk & 0xFFFF);
                float4 bb2 = gBox[p];
                float ba = (bb2.z-bb2.x)*(bb2.w-bb2.y);
                bool sup = false;
                if (lane < na) {
                    float iw = fmaxf(fminf(bb2.z,aB0.z)-fmaxf(bb2.x,aB0.x),0.f);
                    float ih = fmaxf(fminf(bb2.w,aB0.w)-fmaxf(bb2.y,aB0.y),0.f);
                    float in_ = iw*ih;
                    sup = in_/(ba+aA0-in_+1e-12f) > 0.6f;
                }
                if (lane + 64 < na) {
                    float iw = fmaxf(fminf(bb2.z,aB1.z)-fmaxf(bb2.x,aB1.x),0.f);
                    float ih = fmaxf(fminf(bb2.w,aB1.w)-fmaxf(bb2.y,aB1.y),0.f);
                    float in_ = iw*ih;
                    sup = sup || (in_/(ba+aA1-in_+1e-12f) > 0.6f);
                }
                if (__ballot(sup) == 0ULL) {
                    if (lane == 0) {
                        outS[na] = sc;
                        outC[na] = (float)gCls[p];
                        outB[4*na+0]=bb2.x; outB[4*na+1]=bb2.y;
                        outB[4*na+2]=bb2.z; outB[4*na+3]=bb2.w;
                    }
                    if (lane == (na & 63)) {
                        if (na < 64) { aB0 = bb2; aA0 = ba; }
                        else         { aB1 = bb2; aA1 = ba; }
                    }
                    ++na;
                }
                if (lane == 0) cand[bidx] = 0ULL;
                __threadfence_block();
            }
        }
    }
}

extern "C" void kernel_launch(void* const* d_in, const int* in_sizes, int n_in,
                              void* d_out, int out_size, void* d_ws, size_t ws_size,
                              hipStream_t stream) {
    Ptrs P;
    bool interleaved = (in_sizes[1] == 8 * 128 * 128 * 4);
    for (int i = 0; i < 5; ++i) {
        if (interleaved) {
            P.cls[i] = (const float*)d_in[3*i];
            P.reg[i] = (const float*)d_in[3*i + 1];
            P.ctr[i] = (const float*)d_in[3*i + 2];
        } else {
            P.cls[i] = (const float*)d_in[i];
            P.reg[i] = (const float*)d_in[5 + i];
            P.ctr[i] = (const float*)d_in[10 + i];
        }
    }

    char* wbase = (char*)d_ws;
    size_t off = 0;
    auto alloc = [&](size_t bytes) -> void* {
        void* r = wbase + off;
        off += (bytes + 255) & ~(size_t)255;
        return r;
    };
    float*              scoreAll = (float*)alloc((size_t)8 * NPOS * 4);
    int*                clsAll   = (int*)alloc((size_t)8 * NPOS * 4);
    float4*             boxAll   = (float4*)alloc((size_t)8 * NPOS * 16);
    unsigned long long* cKeyG    = (unsigned long long*)alloc((size_t)8 * NC * 8);

    dim3 gA(341, 8);   // 341*64 = 21824 positions, level boundaries block-aligned
    k_score <<<gA, 256, 0, stream>>>(P, scoreAll, clsAll, boxAll);
    k_thresh<<<32, 256, 0, stream>>>(scoreAll, cKeyG);
    k_nms2  <<<8, 256, 0, stream>>>(cKeyG, boxAll, clsAll, (float*)d_out);
}